// Round 5
// baseline (476.803 us; speedup 1.0000x reference)
//
#include <hip/hip_runtime.h>

// Sparsemax along last axis of (4, 4096, 4096) fp32 — two-kernel split.
//
// K1 (tau): wave-per-row. Stream row -> wave max -> compact candidates
//   (x > max-1; tau >= max-1 so nothing else can ever be active; ~14/row
//   for Gaussian) into per-wave LDS -> in-wave Newton on
//   f(tau) = sum(relu(x-tau)) - 1 (monotone from tau0 = max-1, finite
//   convergence, wave-uniform fixed-point exit) -> write tau[row] to ws.
//   Read-only stream: no mixed read/write traffic; second (compact) pass
//   over the row is L2-hot.
//
// K2 (apply): block-per-row elementwise, out = max(x - tau[row], 0).
//   tau is block-uniform (one scalar load). Pure copy-shape kernel;
//   input is L3-resident after K1 (input = 256 MiB = L3 size).
//
// NT stores removed (measured regression R2->R3).

constexpr int D = 4096;
constexpr int BLOCK = 256;
constexpr int WAVES = BLOCK / 64;        // K1: 4 rows per block
constexpr int CHUNKS = D / (64 * 4);     // 16 float4 per lane (K1)
constexpr int NEWTON_ITERS = 16;         // hard cap; exits ~6
constexpr int CAP_W = 512;               // per-wave candidate capacity

__global__ __launch_bounds__(BLOCK) void sparsemax_tau_kernel(
    const float* __restrict__ in, float* __restrict__ tau_out) {
  __shared__ float cand[WAVES][CAP_W];   // 8 KB
  __shared__ int scnt[WAVES];

  const int t = threadIdx.x;
  const int wave = t >> 6;
  const int lane = t & 63;
  const long long row = (long long)blockIdx.x * WAVES + wave;

  const float4* __restrict__ x4 =
      reinterpret_cast<const float4*>(in + row * (long long)D);

  // ---- pass 1: stream row, wave max (butterfly -> all lanes) ----
  float4 v[CHUNKS];
#pragma unroll
  for (int c = 0; c < CHUNKS; c++) v[c] = x4[lane + c * 64];

  float m = -INFINITY;
#pragma unroll
  for (int c = 0; c < CHUNKS; c++)
    m = fmaxf(m, fmaxf(fmaxf(v[c].x, v[c].y), fmaxf(v[c].z, v[c].w)));
#pragma unroll
  for (int o = 32; o > 0; o >>= 1) m = fmaxf(m, __shfl_xor(m, o));
  const float thr = m - 1.0f;  // tau0; no x <= thr can ever be active

  // ---- pass 2: compact candidates into per-wave LDS (wave-lockstep,
  //      no barrier needed; row is L2-hot if the compiler reloads) ----
  if (lane == 0) scnt[wave] = 0;
#pragma unroll
  for (int c = 0; c < CHUNKS; c++) {
    float z;
    z = v[c].x; if (z > thr) { int i = atomicAdd(&scnt[wave], 1); if (i < CAP_W) cand[wave][i] = z; }
    z = v[c].y; if (z > thr) { int i = atomicAdd(&scnt[wave], 1); if (i < CAP_W) cand[wave][i] = z; }
    z = v[c].z; if (z > thr) { int i = atomicAdd(&scnt[wave], 1); if (i < CAP_W) cand[wave][i] = z; }
    z = v[c].w; if (z > thr) { int i = atomicAdd(&scnt[wave], 1); if (i < CAP_W) cand[wave][i] = z; }
  }
  const int n = atomicAdd(&scnt[wave], 0);  // ordered after pushes (DS pipe)

  // ---- Newton, entirely in-wave ----
  float tau = thr;
  if (n <= 64) {
    const float sentinel = thr - 1.0f;  // never > tau (tau >= thr)
    float z = (lane < n) ? cand[wave][lane] : sentinel;
    for (int it = 0; it < NEWTON_ITERS; it++) {
      float S = 0.0f, K = 0.0f;
      if (z > tau) { S = z; K = 1.0f; }
#pragma unroll
      for (int o = 32; o > 0; o >>= 1) {
        S += __shfl_xor(S, o);
        K += __shfl_xor(K, o);
      }
      float tnew = (S - 1.0f) / K;  // K >= 1: x_max = m > tau always
      if (tnew == tau) break;       // wave-uniform exit
      tau = tnew;
    }
  } else if (n <= CAP_W) {
    for (int it = 0; it < NEWTON_ITERS; it++) {
      float S = 0.0f, K = 0.0f;
      for (int i = lane; i < n; i += 64) {
        float z = cand[wave][i];
        if (z > tau) { S += z; K += 1.0f; }
      }
#pragma unroll
      for (int o = 32; o > 0; o >>= 1) {
        S += __shfl_xor(S, o);
        K += __shfl_xor(K, o);
      }
      float tnew = (S - 1.0f) / K;
      if (tnew == tau) break;
      tau = tnew;
    }
  } else {
    // fallback: in-wave Newton over the full row slice (never for Gaussian)
    for (int it = 0; it < NEWTON_ITERS; it++) {
      float S = 0.0f, K = 0.0f;
#pragma unroll
      for (int c = 0; c < CHUNKS; c++) {
        float z;
        z = v[c].x; if (z > tau) { S += z; K += 1.0f; }
        z = v[c].y; if (z > tau) { S += z; K += 1.0f; }
        z = v[c].z; if (z > tau) { S += z; K += 1.0f; }
        z = v[c].w; if (z > tau) { S += z; K += 1.0f; }
      }
#pragma unroll
      for (int o = 32; o > 0; o >>= 1) {
        S += __shfl_xor(S, o);
        K += __shfl_xor(K, o);
      }
      float tnew = (S - 1.0f) / K;
      if (tnew == tau) break;
      tau = tnew;
    }
  }

  if (lane == 0) tau_out[row] = tau;
}

// K2: block b <-> row b. 256 threads x 4 float4 = 4096 floats = one row.
__global__ __launch_bounds__(BLOCK) void sparsemax_apply_kernel(
    const float* __restrict__ in, const float* __restrict__ tau_in,
    float* __restrict__ out) {
  const long long row = blockIdx.x;
  const float tau = tau_in[row];  // block-uniform -> scalar load
  const float4* __restrict__ x4 =
      reinterpret_cast<const float4*>(in + row * (long long)D);
  float4* __restrict__ y4 = reinterpret_cast<float4*>(out + row * (long long)D);
  const int t = threadIdx.x;
#pragma unroll
  for (int c = 0; c < 4; c++) {
    float4 x = x4[t + c * BLOCK];
    float4 o;
    o.x = fmaxf(x.x - tau, 0.0f);
    o.y = fmaxf(x.y - tau, 0.0f);
    o.z = fmaxf(x.z - tau, 0.0f);
    o.w = fmaxf(x.w - tau, 0.0f);
    y4[t + c * BLOCK] = o;
  }
}

extern "C" void kernel_launch(void* const* d_in, const int* in_sizes, int n_in,
                              void* d_out, int out_size, void* d_ws, size_t ws_size,
                              hipStream_t stream) {
  const float* in = (const float*)d_in[0];
  float* out = (float*)d_out;
  float* tau = (float*)d_ws;                   // rows * 4 B = 64 KB
  const int rows = in_sizes[0] / D;            // 16384
  sparsemax_tau_kernel<<<rows / WAVES, BLOCK, 0, stream>>>(in, tau);
  sparsemax_apply_kernel<<<rows, BLOCK, 0, stream>>>(in, tau, out);
}